// Round 5
// baseline (90783.624 us; speedup 1.0000x reference)
//
#include <hip/hip_runtime.h>
#include <math.h>

#define B 32
#define S 512
#define T 128
#define V 32000
#define H 512
#define NB 256          // persistent grid (1 block/CU)
#define NT 1024         // 16 waves/block
#define LCHUNK 250      // logits chunks: 250 blocks x 128 rows

__device__ __forceinline__ float dot4(float acc, float4 a, float4 b){
    return fmaf(a.x,b.x, fmaf(a.y,b.y, fmaf(a.z,b.z, fmaf(a.w,b.w, acc))));
}
__device__ __forceinline__ float sigmoidf_(float x){ return 1.0f/(1.0f+expf(-x)); }

// ---- coherence-point (agent-scope, relaxed) data movers: no cache maintenance
__device__ __forceinline__ float cload1(const float* p){
    unsigned u = __hip_atomic_load((const unsigned*)p, __ATOMIC_RELAXED, __HIP_MEMORY_SCOPE_AGENT);
    return __uint_as_float(u);
}
__device__ __forceinline__ int cloadi(const int* p){
    return (int)__hip_atomic_load((const unsigned*)p, __ATOMIC_RELAXED, __HIP_MEMORY_SCOPE_AGENT);
}
__device__ __forceinline__ float2 cload2(const float* p){
    unsigned long long u = __hip_atomic_load((const unsigned long long*)p, __ATOMIC_RELAXED, __HIP_MEMORY_SCOPE_AGENT);
    float2 f; f.x = __uint_as_float((unsigned)u); f.y = __uint_as_float((unsigned)(u>>32)); return f;
}
__device__ __forceinline__ void cstore1(float* p, float v){
    __hip_atomic_store((unsigned*)p, __float_as_uint(v), __ATOMIC_RELAXED, __HIP_MEMORY_SCOPE_AGENT);
}
__device__ __forceinline__ void cstorei(int* p, int v){
    __hip_atomic_store((unsigned*)p, (unsigned)v, __ATOMIC_RELAXED, __HIP_MEMORY_SCOPE_AGENT);
}

// ---- light barrier: no release, no acquire (data goes through coherent ops)
__device__ __forceinline__ void bar_arrive_l(unsigned* bar){
    __builtin_amdgcn_s_waitcnt(0);      // all coherent stores completed at L3
    __syncthreads();
    if (threadIdx.x == 0)
        __hip_atomic_fetch_add(bar, 1u, __ATOMIC_RELAXED, __HIP_MEMORY_SCOPE_AGENT);
}
__device__ __forceinline__ void bar_wait_l(unsigned* bar, unsigned target){
    if (threadIdx.x == 0){
        long g = 0;
        while (__hip_atomic_load(bar, __ATOMIC_RELAXED, __HIP_MEMORY_SCOPE_AGENT) < target){
            __builtin_amdgcn_s_sleep(2);
            if (++g > 400000000L) break;
        }
    }
    __syncthreads();
}
// ---- heavy barrier (used ONCE, after plain-store combine)
__device__ __forceinline__ void bar_heavy(unsigned* bar, unsigned target){
    __syncthreads();
    if (threadIdx.x == 0){
        __hip_atomic_fetch_add(bar, 1u, __ATOMIC_RELEASE, __HIP_MEMORY_SCOPE_AGENT);
        long g = 0;
        while (__hip_atomic_load(bar, __ATOMIC_RELAXED, __HIP_MEMORY_SCOPE_AGENT) < target){
            __builtin_amdgcn_s_sleep(2);
            if (++g > 400000000L) break;
        }
        (void)__hip_atomic_load(bar, __ATOMIC_ACQUIRE, __HIP_MEMORY_SCOPE_AGENT);
    }
    __syncthreads();
}

// ================= persistent encoder =======================================
// 256 blocks: dir pinned per XCD-half (bk%8), 64 jg x 2 bg per dir.
// 1024 thr: bl(16 b) x kh(8 k-slices of 64) x jj(8 j). Weights stay in L2
// (never invalidated). h exchanged via coherent ops. 1 light barrier/step/dir.
__global__ __launch_bounds__(NT, 4) void enc_persistent(
    const int* __restrict__ input_seq, const float* __restrict__ emb,
    const float* __restrict__ fWih, const float* __restrict__ fWhh,
    const float* __restrict__ fbih, const float* __restrict__ fbhh,
    const float* __restrict__ bWih, const float* __restrict__ bWhh,
    const float* __restrict__ bbih, const float* __restrict__ bbhh,
    float* __restrict__ enc_out, float* __restrict__ out_b, unsigned* bars)
{
    __shared__ __align__(16) float hs[16*516];   // staged h(t-1), padded pitch
    __shared__ float red[128*6];                 // kh cross-wave reduce
    const int bk = blockIdx.x, tid = threadIdx.x;
    const int dir = ((bk & 7) >= 4) ? 1 : 0;
    const int r   = ((bk >> 3) << 2) | (bk & 3);   // 0..127 within dir
    const int jg  = r >> 1, bg = r & 1;
    const int bl  = tid & 15;
    const int kh  = (tid >> 4) & 7;
    const int jj  = tid >> 7;
    const int b   = bg*16 + bl;
    const int j   = jg*8 + jj;

    const float *Wih = dir? bWih : fWih;
    const float *Whh = dir? bWhh : fWhh;
    const float *bih = dir? bbih : fbih;
    const float *bhh = dir? bbhh : fbhh;
    float* outp = dir? out_b : enc_out;
    unsigned* bar = bars + dir*64;

    const float4* wx0 = (const float4*)(Wih + ((size_t)(0*H+j))*H + kh*64);
    const float4* wx1 = (const float4*)(Wih + ((size_t)(1*H+j))*H + kh*64);
    const float4* wx2 = (const float4*)(Wih + ((size_t)(2*H+j))*H + kh*64);
    const float4* wh0 = (const float4*)(Whh + ((size_t)(0*H+j))*H + kh*64);
    const float4* wh1 = (const float4*)(Whh + ((size_t)(1*H+j))*H + kh*64);
    const float4* wh2 = (const float4*)(Whh + ((size_t)(2*H+j))*H + kh*64);
    const float bi_r = bih[j], bi_z = bih[H+j], bi_n = bih[2*H+j];
    const float bh_r = bhh[j], bh_z = bhh[H+j], bh_n = bhh[2*H+j];

    for (int t=0; t<S; t++){
        const int pos  = dir ? (S-1-t) : t;
        const int hpos = dir ? (S-t)   : (t-1);
        const int tok = input_seq[b*S + pos];
        const float4* x4 = (const float4*)(emb + (size_t)tok*H + kh*64);

        float ir=0.f, iz=0.f, in_=0.f;      // x-part before the wait
        #pragma unroll
        for (int k=0;k<16;k++){ const float4 xv=x4[k];
            ir=dot4(ir,xv,wx0[k]); iz=dot4(iz,xv,wx1[k]); in_=dot4(in_,xv,wx2[k]); }

        float hr=0.f, hz=0.f, hn=0.f;
        if (t > 0){
            bar_wait_l(bar, (unsigned)t*128u);
            // stage h(t-1) for the block's 16 b (coherent loads)
            for (int i = tid; i < 4096; i += NT){
                const int bb = i >> 8, k2 = i & 255;
                const float2 v = cload2(outp + ((size_t)(bg*16+bb)*S + hpos)*H + (size_t)k2*2);
                *(float2*)(hs + bb*516 + k2*2) = v;
            }
            __syncthreads();
            const float4* h4 = (const float4*)(hs + bl*516 + kh*64);
            #pragma unroll
            for (int k=0;k<16;k++){ const float4 hv=h4[k];
                hr=dot4(hr,hv,wh0[k]); hz=dot4(hz,hv,wh1[k]); hn=dot4(hn,hv,wh2[k]); }
        }
        // reduce over kh: bits 0,1 in-wave (xor 16/32), bit 2 via LDS
        ir += __shfl_xor(ir,16); iz += __shfl_xor(iz,16); in_ += __shfl_xor(in_,16);
        hr += __shfl_xor(hr,16); hz += __shfl_xor(hz,16); hn  += __shfl_xor(hn ,16);
        ir += __shfl_xor(ir,32); iz += __shfl_xor(iz,32); in_ += __shfl_xor(in_,32);
        hr += __shfl_xor(hr,32); hz += __shfl_xor(hz,32); hn  += __shfl_xor(hn ,32);
        if (kh == 4){
            float* p = red + (jj*16+bl)*6;
            p[0]=ir; p[1]=iz; p[2]=in_; p[3]=hr; p[4]=hz; p[5]=hn;
        }
        __syncthreads();
        if (kh == 0){
            const float* p = red + (jj*16+bl)*6;
            ir+=p[0]; iz+=p[1]; in_+=p[2]; hr+=p[3]; hz+=p[4]; hn+=p[5];
            const float hprev = (t>0) ? hs[bl*516 + j] : 0.0f;
            const float rr_ = sigmoidf_(ir + bi_r + hr + bh_r);
            const float zz  = sigmoidf_(iz + bi_z + hz + bh_z);
            const float nn  = tanhf(in_ + bi_n + rr_*(hn + bh_n));
            cstore1(outp + ((size_t)b*S + pos)*H + j, (1.0f - zz)*nn + zz*hprev);
        }
        __syncthreads();            // red reads done before next-step overwrite
        bar_arrive_l(bar);
    }
}

// ================= persistent decoder =======================================
__global__ __launch_bounds__(NT, 4) void dec_persistent(
    const int* __restrict__ target_seq, const float* __restrict__ emb,
    const float* __restrict__ dWih, const float* __restrict__ dWhh,
    const float* __restrict__ dbih, const float* __restrict__ dbhh,
    const float* __restrict__ attW, const float* __restrict__ attb,
    const float* __restrict__ outW, const float* __restrict__ outBias,
    float* __restrict__ enc_out, const float* __restrict__ out_b,
    float* __restrict__ hdec, float* __restrict__ att_out,
    float* __restrict__ pm, float* __restrict__ ps, int* __restrict__ pidx,
    float* __restrict__ lossb, float* __restrict__ out, unsigned* bar)
{
    __shared__ __align__(16) float smem[16384];    // 64 KB, reused per phase
    const int bk = blockIdx.x, tid = threadIdx.x;
    unsigned tgt = 0;

    // ---- phase 0: hdec0 = hf_last + hb_last (pre-combine) ; loss init ------
    {
        const int gid = bk*NT + tid;
        if (gid < B*H){
            const int bb = gid >> 9, jq = gid & 511;
            cstore1(hdec + gid, enc_out[((size_t)bb*S + (S-1))*H + jq] + out_b[((size_t)bb*S)*H + jq]);
        }
        if (bk==0 && tid<B) lossb[tid] = 0.0f;
    }
    bar_arrive_l(bar); tgt += NB; bar_wait_l(bar, tgt);

    // ---- combine enc_out += out_b (plain), then ONE heavy barrier ----------
    {
        float4* e4 = (float4*)enc_out; const float4* o4 = (const float4*)out_b;
        for (size_t i = (size_t)bk*NT + tid; i < (size_t)B*S*H/4; i += (size_t)NB*NT){
            float4 x = e4[i]; const float4 y = o4[i];
            x.x+=y.x; x.y+=y.y; x.z+=y.z; x.w+=y.w; e4[i]=x;
        }
    }
    tgt += NB; bar_heavy(bar, tgt);

    // G-phase thread decomposition (fixed across steps)
    const int gbl = tid & 15;            // 16 batch lanes
    const int gkh = (tid >> 4) & 15;     // 16 k-slices of 32
    const int gjj = tid >> 8;            // 4 j per block
    const int jgG = bk >> 1, bgG = bk & 1;
    const int jG  = jgG*4 + gjj;
    const int bG  = bgG*16 + gbl;
    const float4* gwx0 = (const float4*)(dWih + ((size_t)(0*H+jG))*H + gkh*32);
    const float4* gwx1 = (const float4*)(dWih + ((size_t)(1*H+jG))*H + gkh*32);
    const float4* gwx2 = (const float4*)(dWih + ((size_t)(2*H+jG))*H + gkh*32);
    const float4* gwh0 = (const float4*)(dWhh + ((size_t)(0*H+jG))*H + gkh*32);
    const float4* gwh1 = (const float4*)(dWhh + ((size_t)(1*H+jG))*H + gkh*32);
    const float4* gwh2 = (const float4*)(dWhh + ((size_t)(2*H+jG))*H + gkh*32);
    const float gbi_r = dbih[jG], gbi_z = dbih[H+jG], gbi_n = dbih[2*H+jG];
    const float gbh_r = dbhh[jG], gbh_z = dbhh[H+jG], gbh_n = dbhh[2*H+jG];

    float* hsG  = smem;                       // 16 x 516
    float* redG = smem + 8256;                // 64 x 18
    int*   sh_tok = (int*)(smem + 9500);      // 32

    for (int t=0; t<T; t++){
        float* hin  = hdec + (size_t)(t&1)*B*H;
        float* hout = hdec + (size_t)((t+1)&1)*B*H;

        // ============ phase G: merge(t-1) -> tokens (+loss blk0), GRU =======
        if (t == 0){
            if (tid < B) sh_tok[tid] = 1;   // SOS
        } else {
            const int mb = tid>>5, p = tid&31;
            float bv = -INFINITY; int ai = 0x7FFFFFFF;
            for (int c=p; c<LCHUNK; c+=32){
                const float v = cload1(pm + mb*LCHUNK + c);
                if (v > bv){ bv = v; ai = cloadi(pidx + mb*LCHUNK + c); }
            }
            #pragma unroll
            for (int m=1; m<32; m<<=1){
                const float ov = __shfl_xor(bv, m); const int oi = __shfl_xor(ai, m);
                if (ov > bv || (ov == bv && oi < ai)){ bv = ov; ai = oi; }
            }
            if (p == 0) sh_tok[mb] = ai;
            if (bk == 0){
                const float MM = bv;        // max of pm over chunks
                float se = 0.0f;
                for (int c=p; c<LCHUNK; c+=32)
                    se += cload1(ps + mb*LCHUNK + c) * expf(cload1(pm + mb*LCHUNK + c) - MM);
                #pragma unroll
                for (int m=1; m<32; m<<=1) se += __shfl_xor(se, m);
                const int tg = target_seq[mb*T + (t-1)];
                const float* arow = att_out + (size_t)mb*H;
                const float* wrow = outW + (size_t)tg*H;
                float d = 0.0f;
                for (int k=p*16; k<p*16+16; k+=2){
                    const float2 av = cload2(arow + k);
                    d = fmaf(av.x, wrow[k], fmaf(av.y, wrow[k+1], d));
                }
                #pragma unroll
                for (int m=1; m<32; m<<=1) d += __shfl_xor(d, m);
                if (p == 0) lossb[mb] += (MM + logf(se)) - (d + outBias[tg]);
            }
        }
        __syncthreads();
        {   // stage hin (coherent) then GRU dots
            for (int i = tid; i < 4096; i += NT){
                const int bb = i >> 8, k2 = i & 255;
                const float2 v = cload2(hin + (size_t)(bgG*16+bb)*H + (size_t)k2*2);
                *(float2*)(hsG + bb*516 + k2*2) = v;
            }
            __syncthreads();
            const int tok = sh_tok[bG];
            const float4* x4 = (const float4*)(emb + (size_t)tok*H + gkh*32);
            const float4* h4 = (const float4*)(hsG + gbl*516 + gkh*32);
            float ir=0.f, iz=0.f, in_=0.f, hr=0.f, hz=0.f, hn=0.f;
            #pragma unroll
            for (int k=0;k<8;k++){
                const float4 xv = x4[k], hv = h4[k];
                ir=dot4(ir,xv,gwx0[k]); iz=dot4(iz,xv,gwx1[k]); in_=dot4(in_,xv,gwx2[k]);
                hr=dot4(hr,hv,gwh0[k]); hz=dot4(hz,hv,gwh1[k]); hn=dot4(hn,hv,gwh2[k]);
            }
            ir += __shfl_xor(ir,16); iz += __shfl_xor(iz,16); in_ += __shfl_xor(in_,16);
            hr += __shfl_xor(hr,16); hz += __shfl_xor(hz,16); hn  += __shfl_xor(hn ,16);
            ir += __shfl_xor(ir,32); iz += __shfl_xor(iz,32); in_ += __shfl_xor(in_,32);
            hr += __shfl_xor(hr,32); hz += __shfl_xor(hz,32); hn  += __shfl_xor(hn ,32);
            const int khq = gkh >> 2;
            if ((gkh & 3) == 0 && khq > 0){
                float* p = redG + (gjj*16+gbl)*18 + (khq-1)*6;
                p[0]=ir; p[1]=iz; p[2]=in_; p[3]=hr; p[4]=hz; p[5]=hn;
            }
            __syncthreads();
            if (gkh == 0){
                #pragma unroll
                for (int q=0;q<3;q++){
                    const float* p = redG + (gjj*16+gbl)*18 + q*6;
                    ir+=p[0]; iz+=p[1]; in_+=p[2]; hr+=p[3]; hz+=p[4]; hn+=p[5];
                }
                const float hprev = hsG[gbl*516 + jG];
                const float rr_ = sigmoidf_(ir + gbi_r + hr + gbh_r);
                const float zz  = sigmoidf_(iz + gbi_z + hz + gbh_z);
                const float nn  = tanhf(in_ + gbi_n + rr_*(hn + gbh_n));
                cstore1(hout + (size_t)bG*H + jG, (1.0f - zz)*nn + zz*hprev);
            }
            __syncthreads();
        }
        bar_arrive_l(bar); tgt += NB; bar_wait_l(bar, tgt);

        // ============ phase A: scores+softmax+ctx+proj (1 block per b) ======
        if (bk < B){
            const int b = bk;
            float* sc  = smem;          // 512 weights
            float* cat = smem + 512;    // [ctx(512) | hn(512)]
            float* rr  = smem + 1536;   // 1024 reduce scratch
            if (tid < 256){
                const float2 v = cload2(hout + (size_t)b*H + tid*2);
                cat[512 + tid*2] = v.x; cat[512 + tid*2 + 1] = v.y;
            }
            __syncthreads();
            // scores
            {
                const int s = tid >> 1, hf = tid & 1;
                const float4* e4 = (const float4*)(enc_out + ((size_t)b*S + s)*H + hf*256);
                const float4* h4 = (const float4*)(cat + 512 + hf*256);
                float a0=0.f,a1=0.f,a2=0.f,a3=0.f;
                #pragma unroll
                for (int k=0;k<64;k+=4){
                    a0=dot4(a0,h4[k  ],e4[k  ]); a1=dot4(a1,h4[k+1],e4[k+1]);
                    a2=dot4(a2,h4[k+2],e4[k+2]); a3=dot4(a3,h4[k+3],e4[k+3]);
                }
                float a = (a0+a1)+(a2+a3);
                a += __shfl_xor(a, 1);
                if (hf == 0) sc[s] = a;
            }
            __syncthreads();
            // softmax over 512
            rr[tid] = (tid < 512) ? sc[tid] : -INFINITY; __syncthreads();
            for (int off=512; off>0; off>>=1){ if (tid<off) rr[tid]=fmaxf(rr[tid],rr[tid+off]); __syncthreads(); }
            const float M = rr[0]; __syncthreads();
            if (tid < 512) sc[tid] = expf(sc[tid]-M);
            __syncthreads();
            rr[tid] = (tid < 512) ? sc[tid] : 0.0f; __syncthreads();
            for (int off=512; off>0; off>>=1){ if (tid<off) rr[tid]+=rr[tid+off]; __syncthreads(); }
            const float inv = 1.0f/rr[0]; __syncthreads();
            if (tid < 512) sc[tid] *= inv;
            __syncthreads();
            // ctx
            {
                const int col = tid & 511, sg = tid >> 9;
                const float* Ec = enc_out + (size_t)b*S*H + col;
                float a0=0.f,a1=0.f,a2=0.f,a3=0.f;
                for (int s2=sg; s2<512; s2+=8){
                    a0 = fmaf(sc[s2  ], Ec[(size_t)(s2  )*H], a0);
                    a1 = fmaf(sc[s2+2], Ec[(size_t)(s2+2)*H], a1);
                    a2 = fmaf(sc[s2+4], Ec[(size_t)(s2+4)*H], a2);
                    a3 = fmaf(sc[s2+6], Ec[(size_t)(s2+6)*H], a3);
                }
                rr[tid] = (a0+a1)+(a2+a3);
            }
            __syncthreads();
            if (tid < 512) cat[tid] = rr[tid] + rr[tid+512];
            __syncthreads();
            // proj
            {
                const int row = tid >> 1, hf = tid & 1;
                const float4* w4 = (const float4*)(attW + (size_t)row*(2*H) + hf*512);
                const float4* c4 = (const float4*)(cat + hf*512);
                float a0=0.f,a1=0.f,a2=0.f,a3=0.f;
                #pragma unroll
                for (int k=0;k<128;k+=4){
                    a0=dot4(a0,c4[k  ],w4[k  ]); a1=dot4(a1,c4[k+1],w4[k+1]);
                    a2=dot4(a2,c4[k+2],w4[k+2]); a3=dot4(a3,c4[k+3],w4[k+3]);
                }
                float a = (a0+a1)+(a2+a3);
                a += __shfl_xor(a, 1);
                if (hf == 0) cstore1(att_out + (size_t)b*H + row, tanhf(a + attb[row]));
            }
        }
        bar_arrive_l(bar); tgt += NB; bar_wait_l(bar, tgt);

        // ============ phase L: logits partials ==============================
        if (bk < LCHUNK){
            float* sha = smem;      // 32 x 512 staged att_out (broadcast reads)
            for (int i = tid; i < 8192; i += NT){
                const int bb = i >> 8, k2 = i & 255;
                const float2 v = cload2(att_out + (size_t)bb*H + k2*2);
                *(float2*)(sha + bb*512 + k2*2) = v;
            }
            __syncthreads();
            const int rg = tid & 31, bg = tid >> 5;
            const int r0 = bk*128 + rg;
            const float4* w0 = (const float4*)(outW + (size_t)(r0     )*H);
            const float4* w1 = (const float4*)(outW + (size_t)(r0 + 32)*H);
            const float4* w2 = (const float4*)(outW + (size_t)(r0 + 64)*H);
            const float4* w3 = (const float4*)(outW + (size_t)(r0 + 96)*H);
            const float4* a4 = (const float4*)(sha + bg*512);
            float c0=0.f,c1=0.f,c2=0.f,c3=0.f;
            #pragma unroll 4
            for (int k=0;k<128;k++){
                const float4 av = a4[k];
                c0 = dot4(c0, av, w0[k]);
                c1 = dot4(c1, av, w1[k]);
                c2 = dot4(c2, av, w2[k]);
                c3 = dot4(c3, av, w3[k]);
            }
            const float l0 = c0 + outBias[r0];
            const float l1 = c1 + outBias[r0+32];
            const float l2 = c2 + outBias[r0+64];
            const float l3 = c3 + outBias[r0+96];
            float M = fmaxf(fmaxf(l0,l1), fmaxf(l2,l3));
            #pragma unroll
            for (int m=1;m<32;m<<=1) M = fmaxf(M, __shfl_xor(M, m));
            float sum = expf(l0-M)+expf(l1-M)+expf(l2-M)+expf(l3-M);
            #pragma unroll
            for (int m=1;m<32;m<<=1) sum += __shfl_xor(sum, m);
            float bv = l0; int bi = r0;
            if (l1 > bv){ bv=l1; bi=r0+32; }
            if (l2 > bv){ bv=l2; bi=r0+64; }
            if (l3 > bv){ bv=l3; bi=r0+96; }
            #pragma unroll
            for (int m=1;m<32;m<<=1){
                const float ov = __shfl_xor(bv, m); const int oi = __shfl_xor(bi, m);
                if (ov > bv || (ov == bv && oi < bi)){ bv=ov; bi=oi; }
            }
            if (rg == 0){
                cstore1(pm  + bg*LCHUNK + bk, M);
                cstore1(ps  + bg*LCHUNK + bk, sum);
                cstorei(pidx+ bg*LCHUNK + bk, bi);
            }
            __syncthreads();
        }
        bar_arrive_l(bar); tgt += NB; bar_wait_l(bar, tgt);
    }

    // ---- epilogue: block 0 adds step T-1 loss and writes the mean ----------
    if (bk == 0){
        const int mb = tid>>5, p = tid&31;
        float bv = -INFINITY;
        for (int c=p; c<LCHUNK; c+=32) bv = fmaxf(bv, cload1(pm + mb*LCHUNK + c));
        #pragma unroll
        for (int m=1;m<32;m<<=1) bv = fmaxf(bv, __shfl_xor(bv, m));
        float se = 0.0f;
        for (int c=p; c<LCHUNK; c+=32)
            se += cload1(ps + mb*LCHUNK + c) * expf(cload1(pm + mb*LCHUNK + c) - bv);
        #pragma unroll
        for (int m=1;m<32;m<<=1) se += __shfl_xor(se, m);
        const int tg = target_seq[mb*T + (T-1)];
        const float* arow = att_out + (size_t)mb*H;
        const float* wrow = outW + (size_t)tg*H;
        float d = 0.0f;
        for (int k=p*16; k<p*16+16; k+=2){
            const float2 av = cload2(arow + k);
            d = fmaf(av.x, wrow[k], fmaf(av.y, wrow[k+1], d));
        }
        #pragma unroll
        for (int m=1;m<32;m<<=1) d += __shfl_xor(d, m);
        if (p == 0) lossb[mb] += (bv + logf(se)) - (d + outBias[tg]);
        __syncthreads();
        if (tid < B){
            float v = lossb[tid];
            #pragma unroll
            for (int off=16; off>0; off>>=1) v += __shfl_down(v, off);
            if (tid == 0) out[0] = v / (float)(B*T);
        }
    }
}

extern "C" void kernel_launch(void* const* d_in, const int* in_sizes, int n_in,
                              void* d_out, int out_size, void* d_ws, size_t ws_size,
                              hipStream_t stream)
{
    const int*   input_seq  = (const int*)  d_in[0];
    const int*   target_seq = (const int*)  d_in[1];
    const float* emb    = (const float*)d_in[2];
    const float* efWih  = (const float*)d_in[3];
    const float* efWhh  = (const float*)d_in[4];
    const float* efbih  = (const float*)d_in[5];
    const float* efbhh  = (const float*)d_in[6];
    const float* ebWih  = (const float*)d_in[7];
    const float* ebWhh  = (const float*)d_in[8];
    const float* ebbih  = (const float*)d_in[9];
    const float* ebbhh  = (const float*)d_in[10];
    const float* dWih   = (const float*)d_in[11];
    const float* dWhh   = (const float*)d_in[12];
    const float* dbih   = (const float*)d_in[13];
    const float* dbhh   = (const float*)d_in[14];
    const float* attW   = (const float*)d_in[15];
    const float* attb   = (const float*)d_in[16];
    const float* outW   = (const float*)d_in[17];
    const float* outBias= (const float*)d_in[18];

    float* ws      = (float*)d_ws;
    unsigned* bars = (unsigned*)ws;                    // [0]=enc d0, [64]=enc d1, [128]=dec
    float* enc_out = ws + 1024;                        // B*S*H
    float* outb    = enc_out + (size_t)B*S*H;          // B*S*H
    float* attout  = outb    + (size_t)B*S*H;          // B*H
    float* pm      = attout  + (size_t)B*H;            // B*LCHUNK
    float* psum    = pm      + (size_t)B*LCHUNK;       // B*LCHUNK
    int*   pidx    = (int*)(psum + (size_t)B*LCHUNK);  // B*LCHUNK
    float* hdec    = (float*)(pidx + (size_t)B*LCHUNK);// 2*B*H
    float* lossb   = hdec    + (size_t)2*B*H;          // B

    hipMemsetAsync(bars, 0, 4096, stream);

    enc_persistent<<<NB, NT, 0, stream>>>(input_seq, emb,
        efWih, efWhh, efbih, efbhh, ebWih, ebWhh, ebbih, ebbhh,
        enc_out, outb, bars);

    dec_persistent<<<NB, NT, 0, stream>>>(target_seq, emb,
        dWih, dWhh, dbih, dbhh, attW, attb, outW, outBias,
        enc_out, outb, hdec, attout, pm, psum, pidx,
        lossb, (float*)d_out, bars + 128);
}